// Round 19
// baseline (216.527 us; speedup 1.0000x reference)
//
#include <hip/hip_runtime.h>

typedef _Float16 f16;
typedef __attribute__((ext_vector_type(8))) _Float16 h8;
typedef __attribute__((ext_vector_type(4))) _Float16 h4;
typedef __attribute__((ext_vector_type(8))) short s8;     // 8 bf16 (4 VGPRs)
typedef __attribute__((ext_vector_type(4))) unsigned short u16x4;
typedef __attribute__((ext_vector_type(4))) float f4;
typedef __attribute__((ext_vector_type(16))) float f16x;
typedef __attribute__((ext_vector_type(4))) unsigned u4;

#define MFMA(a, b, c) __builtin_amdgcn_mfma_f32_16x16x32_f16(a, b, c, 0, 0, 0)
#define MFMA32(a, b, c) __builtin_amdgcn_mfma_f32_32x32x16_f16(a, b, c, 0, 0, 0)
#define MFMA32B(a, b, c) __builtin_amdgcn_mfma_f32_32x32x16_bf16(a, b, c, 0, 0, 0)

// Q prescale: 1/sqrt(64) * log2(e), folded into qkv epilogue -> softmax in base-2
#define QSCALE 0.18033688011112042f

__device__ __forceinline__ void gload16(const void* g, void* l) {
    __builtin_amdgcn_global_load_lds((const __attribute__((address_space(1))) void*)g,
                                     (__attribute__((address_space(3))) void*)l, 16, 0, 0);
}

__device__ __forceinline__ float fexp2(float x) {
    float r;
    asm("v_exp_f32 %0, %1" : "=v"(r) : "v"(x));
    return r;
}

// pack 2 f32 -> 2 bf16 in one u32 (low = src0)
__device__ __forceinline__ unsigned pkb(float a, float b) {
    unsigned r;
    asm("v_cvt_pk_bf16_f32 %0, %1, %2" : "=v"(r) : "v"(a), "v"(b));
    return r;
}

// f32 -> bf16 with round-to-nearest-even
__device__ __forceinline__ unsigned short bf16rn(float x) {
    unsigned u = __builtin_bit_cast(unsigned, x);
    u += 0x7fffu + ((u >> 16) & 1u);
    return (unsigned short)(u >> 16);
}

// v_permlane32_swap_b32: a[l>=32] <-> b[l<32]  (both operands modified)
__device__ __forceinline__ void plswap(unsigned& a, unsigned& b) {
    asm volatile("v_permlane32_swap_b32 %0, %1" : "+v"(a), "+v"(b));
}

// ---------------- conversion kernels ----------------

__global__ __launch_bounds__(256) void cvt_f16_kernel(const float* __restrict__ in,
                                                      f16* __restrict__ out, int n8) {
    int i = blockIdx.x * blockDim.x + threadIdx.x;
    if (i >= n8) return;
    const float4* p = (const float4*)in + (size_t)i * 2;
    float4 a = p[0], b = p[1];
    h8 o;
    o[0] = (f16)a.x; o[1] = (f16)a.y; o[2] = (f16)a.z; o[3] = (f16)a.w;
    o[4] = (f16)b.x; o[5] = (f16)b.y; o[6] = (f16)b.z; o[7] = (f16)b.w;
    *((h8*)out + i) = o;
}

// in: [R][Cc] f32 row-major -> out: [Cc][R] f16 row-major
__global__ __launch_bounds__(256) void transpose_cvt(const float* __restrict__ in,
                                                     f16* __restrict__ out, int R, int Cc) {
    __shared__ float tile[32][33];
    int tx = threadIdx.x, ty = threadIdx.y;
    int c0 = blockIdx.x * 32, r0 = blockIdx.y * 32;
#pragma unroll
    for (int k = 0; k < 32; k += 8)
        tile[ty + k][tx] = in[(size_t)(r0 + ty + k) * Cc + c0 + tx];
    __syncthreads();
#pragma unroll
    for (int k = 0; k < 32; k += 8)
        out[(size_t)(c0 + ty + k) * R + r0 + tx] = (f16)tile[tx][ty + k];
}

// ---------------- GEMM core (128x128 tile, BK=64, 4 waves, swizzled LDS) ----------------

__device__ __forceinline__ void gemm_core(const f16* __restrict__ A, const f16* __restrict__ Bt,
                                          int K, int m0, int n0,
                                          f16* lA, f16* lB, f4 acc[4][4]) {
    const int tid = threadIdx.x, lane = tid & 63, wave = tid >> 6;
    const int wm = (wave >> 1) * 64, wn = (wave & 1) * 64;
    for (int k0 = 0; k0 < K; k0 += 64) {
        __syncthreads();
#pragma unroll
        for (int i = 0; i < 4; i++) {
            int s = i * 256 + wave * 64 + lane;
            int row = s >> 3;
            int gc = ((s & 7) ^ (row & 7)) * 8;
            gload16(A + (size_t)(m0 + row) * K + k0 + gc, lA + (i * 256 + wave * 64) * 8);
        }
#pragma unroll
        for (int i = 0; i < 4; i++) {
            int s = i * 256 + wave * 64 + lane;
            int row = s >> 3;
            int gc = ((s & 7) ^ (row & 7)) * 8;
            gload16(Bt + (size_t)(n0 + row) * K + k0 + gc, lB + (i * 256 + wave * 64) * 8);
        }
        __syncthreads();
#pragma unroll
        for (int kk = 0; kk < 2; kk++) {
            h8 af[4], bg[4];
#pragma unroll
            for (int im = 0; im < 4; im++) {
                int row = wm + im * 16 + (lane & 15);
                int pc = (kk * 4 + (lane >> 4)) ^ (row & 7);
                af[im] = *(const h8*)(lA + row * 64 + pc * 8);
            }
#pragma unroll
            for (int in = 0; in < 4; in++) {
                int row = wn + in * 16 + (lane & 15);
                int pc = (kk * 4 + (lane >> 4)) ^ (row & 7);
                bg[in] = *(const h8*)(lB + row * 64 + pc * 8);
            }
#pragma unroll
            for (int im = 0; im < 4; im++)
#pragma unroll
                for (int in = 0; in < 4; in++)
                    acc[im][in] = MFMA(af[im], bg[in], acc[im][in]);
        }
    }
}

// ---------------- QKV GEMM: Q (prescaled), K [BH][T][64] f16; V [BH][T/32][64][32] bf16 ----------------

__global__ __launch_bounds__(256) void qkv_gemm(const f16* __restrict__ A, const f16* __restrict__ Bt,
                                                const float* __restrict__ bias,
                                                f16* __restrict__ Qo, f16* __restrict__ Ko,
                                                unsigned short* __restrict__ Vo) {
    __shared__ f16 lA[128 * 64], lB[128 * 64];
    f4 acc[4][4];
    const f4 zz = {0.f, 0.f, 0.f, 0.f};
#pragma unroll
    for (int i = 0; i < 4; i++)
#pragma unroll
        for (int j = 0; j < 4; j++) acc[i][j] = zz;

    const int swz = (blockIdx.x & 7) * 192 + (blockIdx.x >> 3);  // XCD-chunked (1536 = 8*192)
    const int nb = swz % 24, mb = swz / 24;
    gemm_core(A, Bt, 1024, mb * 128, nb * 128, lA, lB, acc);

    const int lane = threadIdx.x & 63, wave = threadIdx.x >> 6;
    const int wm = (wave >> 1) * 64, wn = (wave & 1) * 64;
#pragma unroll
    for (int im = 0; im < 4; im++) {
        int m4 = mb * 128 + wm + im * 16 + (lane >> 4) * 4;
        int b = m4 >> 11, t0 = m4 & 2047;
#pragma unroll
        for (int in = 0; in < 4; in++) {
            int n = nb * 128 + wn + in * 16 + (lane & 15);
            float bb = bias[n];
            int sec = n >> 10, cc = n & 1023, hh = cc >> 6, d = cc & 63;
            if (sec == 2) {
                // V tiled [kt][64][32] bf16: addr = bh*131072 + (t/32)*2048 + d*32 + (t&31)
                u16x4 pv;
#pragma unroll
                for (int r = 0; r < 4; r++) pv[r] = bf16rn(acc[im][in][r] + bb);
                *(u16x4*)(Vo + (size_t)(b * 16 + hh) * 131072 + (t0 >> 5) * 2048 + d * 32 +
                          (t0 & 31)) = pv;
            } else {
                f16* dst = sec ? Ko : Qo;
                float sc = sec ? 1.0f : QSCALE;  // Q prescaled for base-2 softmax
                size_t base = ((size_t)(b * 16 + hh) * 2048 + t0) * 64 + d;
#pragma unroll
                for (int r = 0; r < 4; r++)
                    dst[base + (size_t)r * 64] = (f16)((acc[im][in][r] + bb) * sc);
            }
        }
    }
}

// ---------------- Proj GEMM: f32 output + bias ----------------

__global__ __launch_bounds__(256) void proj_gemm(const f16* __restrict__ A, const f16* __restrict__ Bt,
                                                 const float* __restrict__ bias,
                                                 float* __restrict__ out) {
    __shared__ f16 lA[128 * 64], lB[128 * 64];
    f4 acc[4][4];
    const f4 zz = {0.f, 0.f, 0.f, 0.f};
#pragma unroll
    for (int i = 0; i < 4; i++)
#pragma unroll
        for (int j = 0; j < 4; j++) acc[i][j] = zz;

    const int swz = (blockIdx.x & 7) * 64 + (blockIdx.x >> 3);  // XCD-chunked (512 = 8*64)
    const int nb = swz & 7, mb = swz >> 3;
    gemm_core(A, Bt, 1024, mb * 128, nb * 128, lA, lB, acc);

    const int lane = threadIdx.x & 63, wave = threadIdx.x >> 6;
    const int wm = (wave >> 1) * 64, wn = (wave & 1) * 64;
#pragma unroll
    for (int im = 0; im < 4; im++) {
        int m4 = mb * 128 + wm + im * 16 + (lane >> 4) * 4;
#pragma unroll
        for (int in = 0; in < 4; in++) {
            int n = nb * 128 + wn + in * 16 + (lane & 15);
            float bb = bias[n];
#pragma unroll
            for (int r = 0; r < 4; r++)
                out[(size_t)(m4 + r) * 1024 + n] = acc[im][in][r] + bb;
        }
    }
}

// ---------------- Flash attention: ALL-REGISTER, zero LDS, one-tile-ahead K+V ----------------
// Q(prescaled),K: [BH][2048][64] f16; V: [BH][T/32][64][32] bf16 (kt-tiled); O: [B][2048][1024] f16
// Grid 2048 x 64 threads: block p does q-tiles (63-p) then (p); uniform 65 tiles/block;
// 8 blocks/CU flat; waves fully independent. NO LDS AT ALL: K and V fragments load
// global->registers one tile ahead (named ping-pong sets, rule #20), vmcnt(8) waits only
// last tile's 8 loads. K A-fragment K[k0+ln][dd*16+hi*8] = 16B/lane, full 64B-line use;
// V kt-tiled layout makes PV reads lane-consecutive (kills the 4KB-stride 4x L2 over-read).
// No-max bf16 softmax (R18): P = 2^S, PV in bf16 MFMA; tree-sum for l.

#define ASM_VMCNT(N) asm volatile("s_waitcnt vmcnt(" #N ")" ::: "memory")

__device__ __forceinline__ void attn_tile(int k0, bool last, bool stage_next,
                                          int lane, int hi, int ln,
                                          const f16* __restrict__ Kb,
                                          const unsigned short* __restrict__ Vb,
                                          const h8 (&qf)[4],
                                          h8 (&kf)[4], h8 (&kfn)[4],
                                          s8 (&vf)[2][2], s8 (&vfn)[2][2],
                                          float& lpart, f16x& y0, f16x& y1) {
    if (stage_next) {
        const int kn = k0 + 32;
        // K(it+1) -> other register set (4 x dwordx4); lane reads row kn+ln, chunk dd
#pragma unroll
        for (int dd = 0; dd < 4; dd++)
            kfn[dd] = *(const h8*)(Kb + (size_t)(kn + ln) * 64 + dd * 16 + hi * 8);
        // V(it+1) -> other register set (4 x dwordx4); kt-tiled: lane-consecutive lines
#pragma unroll
        for (int ks = 0; ks < 2; ks++)
#pragma unroll
            for (int j = 0; j < 2; j++)
                vfn[ks][j] = *(const s8*)(Vb + (size_t)(kn >> 5) * 2048 + (j * 32 + ln) * 32 +
                                          ks * 16 + hi * 8);
        ASM_VMCNT(8);  // wait only last tile's 8 loads; current 8 stay in flight
    } else {
        ASM_VMCNT(0);
    }
    __builtin_amdgcn_sched_barrier(0);

    // S^T = K.Q^T (A = K rows in regs, B = Q regs); lane owns q = qw+ln
    f16x s0;
#pragma unroll
    for (int r = 0; r < 16; r++) s0[r] = 0.f;
    __builtin_amdgcn_s_setprio(1);
#pragma unroll
    for (int dd = 0; dd < 4; dd++) s0 = MFMA32(kf[dd], qf[dd], s0);
    __builtin_amdgcn_s_setprio(0);

    if (last) {  // diagonal tile (k0 == qw): mask k-local kl > ln
#pragma unroll
        for (int r = 0; r < 16; r++) {
            int kl = (r & 3) + 8 * (r >> 2) + 4 * hi;
            if (kl > ln) s0[r] = -3e38f;
        }
    }

    // no-shift softmax: P = 2^S (bf16 keeps relative precision at any scale); tree-sum l
    float ps[16];
#pragma unroll
    for (int r = 0; r < 16; r++) {
        ps[r] = fexp2(s0[r]);
        s0[r] = ps[r];
    }
#pragma unroll
    for (int m = 1; m < 16; m <<= 1)
#pragma unroll
        for (int r = 0; r < 16; r += 2 * m) ps[r] += ps[r + m];
    lpart += ps[0];

    // P -> PV A-fragments (bf16): 8 cvt_pk_bf16 + 4 permlane32_swap (layout as R9)
    s8 pa[2];
    {
        unsigned a0 = pkb(s0[0], s0[1]), a1 = pkb(s0[2], s0[3]);
        unsigned b0 = pkb(s0[4], s0[5]), b1 = pkb(s0[6], s0[7]);
        plswap(a0, b0); plswap(a1, b1);
        u4 w0; w0[0] = a0; w0[1] = a1; w0[2] = b0; w0[3] = b1;
        pa[0] = __builtin_bit_cast(s8, w0);
        unsigned c0 = pkb(s0[8], s0[9]), c1 = pkb(s0[10], s0[11]);
        unsigned d0 = pkb(s0[12], s0[13]), d1 = pkb(s0[14], s0[15]);
        plswap(c0, d0); plswap(c1, d1);
        u4 w1; w1[0] = c0; w1[1] = c1; w1[2] = d0; w1[3] = d1;
        pa[1] = __builtin_bit_cast(s8, w1);
    }

    // Y += P V  (V prefetched into regs one tile ago; no wait needed)
    __builtin_amdgcn_s_setprio(1);
#pragma unroll
    for (int ks = 0; ks < 2; ks++) {
        y0 = MFMA32B(pa[ks], vf[ks][0], y0);
        y1 = MFMA32B(pa[ks], vf[ks][1], y1);
    }
    __builtin_amdgcn_s_setprio(0);
}

__global__ __launch_bounds__(64) void attn_kernel(const f16* __restrict__ Q,
                                                  const f16* __restrict__ K,
                                                  const unsigned short* __restrict__ Vg,
                                                  f16* __restrict__ O) {
    const int lane = threadIdx.x;
    const int hi = lane >> 5, ln = lane & 31;
    const int bh = blockIdx.x & 63;
    const int p = (int)(blockIdx.x >> 6);  // 0..31
    const f16* Qb = Q + (size_t)bh * 2048 * 64;
    const f16* Kb = K + (size_t)bh * 2048 * 64;
    const unsigned short* Vb = Vg + (size_t)bh * 131072;
    const int b = bh >> 4, hh = bh & 15;

    for (int ph = 0; ph < 2; ph++) {
        const int qt = ph ? p : 63 - p;  // complementary pair: total 65 tiles/block, uniform
        const int qw = qt * 32;

        // hoist Q fragments (B-operand): Q[qw+ln][dd*16 + hi*8 .. +8]
        h8 qf[4];
#pragma unroll
        for (int dd = 0; dd < 4; dd++)
            qf[dd] = *(const h8*)(Qb + (size_t)(qw + ln) * 64 + dd * 16 + hi * 8);

        float lpart = 0.f;
        f16x y0, y1;
#pragma unroll
        for (int r = 0; r < 16; r++) { y0[r] = 0.f; y1[r] = 0.f; }

        const int nt = qt + 1;  // tiles of 32; last tile k0 == qw

        // prologue: K(0) -> kfA, V(0) -> vfA
        h8 kfA[4], kfB[4];
        s8 vfA[2][2], vfB[2][2];
#pragma unroll
        for (int dd = 0; dd < 4; dd++)
            kfA[dd] = *(const h8*)(Kb + (size_t)ln * 64 + dd * 16 + hi * 8);
#pragma unroll
        for (int ks = 0; ks < 2; ks++)
#pragma unroll
            for (int j = 0; j < 2; j++)
                vfA[ks][j] = *(const s8*)(Vb + (size_t)(j * 32 + ln) * 32 + ks * 16 + hi * 8);

        for (int it = 0; it < nt; it += 2) {
            attn_tile(it * 32, it == nt - 1, it + 1 < nt, lane, hi, ln, Kb, Vb,
                      qf, kfA, kfB, vfA, vfB, lpart, y0, y1);
            if (it + 1 < nt)
                attn_tile((it + 1) * 32, it + 1 == nt - 1, it + 2 < nt, lane, hi, ln, Kb, Vb,
                          qf, kfB, kfA, vfB, vfA, lpart, y0, y1);
        }

        // phase epilogue: combine half-lane partials, normalize, store
        float lT = lpart + __shfl_xor(lpart, 32);
        float inv = 1.0f / lT;
#pragma unroll
        for (int r = 0; r < 16; r++) {
            int crow = (r & 3) + 8 * (r >> 2) + 4 * hi;
            float invr = __shfl(inv, crow);
            size_t base = ((size_t)(b * 2048 + qw + crow)) * 1024 + hh * 64 + ln;
            O[base] = (f16)(y0[r] * invr);
            O[base + 32] = (f16)(y1[r] * invr);
        }
    }
}

// ---------------- launch ----------------

extern "C" void kernel_launch(void* const* d_in, const int* in_sizes, int n_in,
                              void* d_out, int out_size, void* d_ws, size_t ws_size,
                              hipStream_t stream) {
    const float* x      = (const float*)d_in[0];
    const float* W_attn = (const float*)d_in[1];
    const float* b_attn = (const float*)d_in[2];
    const float* W_proj = (const float*)d_in[3];
    const float* b_proj = (const float*)d_in[4];
    float* out = (float*)d_out;

    char* ws = (char*)d_ws;
    f16* xb  = (f16*)ws;                                   // 16 MB (reused as attn out)
    f16* Wat = (f16*)(ws + 16777216);                      // 6 MB
    f16* Wpt = (f16*)(ws + 16777216 + 6291456);            // 2 MB
    unsigned short* Vt = (unsigned short*)(ws + 16777216 + 6291456 + 2097152);  // 16 MB (bf16)
    f16* Qs  = (f16*)d_out;                                // scratch: first 16 MB of out
    f16* Ks  = (f16*)((char*)d_out + 16777216);            // scratch: second 16 MB of out

    cvt_f16_kernel<<<4096, 256, 0, stream>>>(x, xb, 1048576);
    transpose_cvt<<<dim3(96, 32), dim3(32, 8), 0, stream>>>(W_attn, Wat, 1024, 3072);
    transpose_cvt<<<dim3(32, 32), dim3(32, 8), 0, stream>>>(W_proj, Wpt, 1024, 1024);
    qkv_gemm<<<1536, 256, 0, stream>>>(xb, Wat, b_attn, Qs, Ks, Vt);
    attn_kernel<<<2048, 64, 0, stream>>>(Qs, Ks, Vt, xb);
    proj_gemm<<<512, 256, 0, stream>>>(xb, Wpt, b_proj, out);
}

// Round 20
// 201.489 us; speedup vs baseline: 1.0746x; 1.0746x over previous
//
#include <hip/hip_runtime.h>

typedef _Float16 f16;
typedef __attribute__((ext_vector_type(8))) _Float16 h8;
typedef __attribute__((ext_vector_type(4))) _Float16 h4;
typedef __attribute__((ext_vector_type(8))) short s8;     // 8 bf16 (4 VGPRs)
typedef __attribute__((ext_vector_type(4))) unsigned short u16x4;
typedef __attribute__((ext_vector_type(4))) float f4;
typedef __attribute__((ext_vector_type(16))) float f16x;
typedef __attribute__((ext_vector_type(4))) unsigned u4;

#define MFMA(a, b, c) __builtin_amdgcn_mfma_f32_16x16x32_f16(a, b, c, 0, 0, 0)
#define MFMA32(a, b, c) __builtin_amdgcn_mfma_f32_32x32x16_f16(a, b, c, 0, 0, 0)
#define MFMA32B(a, b, c) __builtin_amdgcn_mfma_f32_32x32x16_bf16(a, b, c, 0, 0, 0)

// Q prescale: 1/sqrt(64) * log2(e), folded into qkv epilogue -> softmax in base-2
#define QSCALE 0.18033688011112042f

__device__ __forceinline__ void gload16(const void* g, void* l) {
    __builtin_amdgcn_global_load_lds((const __attribute__((address_space(1))) void*)g,
                                     (__attribute__((address_space(3))) void*)l, 16, 0, 0);
}

__device__ __forceinline__ float fexp2(float x) {
    float r;
    asm("v_exp_f32 %0, %1" : "=v"(r) : "v"(x));
    return r;
}

// pack 2 f32 -> 2 bf16 in one u32 (low = src0)
__device__ __forceinline__ unsigned pkb(float a, float b) {
    unsigned r;
    asm("v_cvt_pk_bf16_f32 %0, %1, %2" : "=v"(r) : "v"(a), "v"(b));
    return r;
}

// f32 -> bf16 with round-to-nearest-even
__device__ __forceinline__ unsigned short bf16rn(float x) {
    unsigned u = __builtin_bit_cast(unsigned, x);
    u += 0x7fffu + ((u >> 16) & 1u);
    return (unsigned short)(u >> 16);
}

// v_permlane32_swap_b32: a[l>=32] <-> b[l<32]  (both operands modified)
__device__ __forceinline__ void plswap(unsigned& a, unsigned& b) {
    asm volatile("v_permlane32_swap_b32 %0, %1" : "+v"(a), "+v"(b));
}

// ---------------- conversion kernels ----------------

__global__ __launch_bounds__(256) void cvt_f16_kernel(const float* __restrict__ in,
                                                      f16* __restrict__ out, int n8) {
    int i = blockIdx.x * blockDim.x + threadIdx.x;
    if (i >= n8) return;
    const float4* p = (const float4*)in + (size_t)i * 2;
    float4 a = p[0], b = p[1];
    h8 o;
    o[0] = (f16)a.x; o[1] = (f16)a.y; o[2] = (f16)a.z; o[3] = (f16)a.w;
    o[4] = (f16)b.x; o[5] = (f16)b.y; o[6] = (f16)b.z; o[7] = (f16)b.w;
    *((h8*)out + i) = o;
}

// in: [R][Cc] f32 row-major -> out: [Cc][R] f16 row-major
__global__ __launch_bounds__(256) void transpose_cvt(const float* __restrict__ in,
                                                     f16* __restrict__ out, int R, int Cc) {
    __shared__ float tile[32][33];
    int tx = threadIdx.x, ty = threadIdx.y;
    int c0 = blockIdx.x * 32, r0 = blockIdx.y * 32;
#pragma unroll
    for (int k = 0; k < 32; k += 8)
        tile[ty + k][tx] = in[(size_t)(r0 + ty + k) * Cc + c0 + tx];
    __syncthreads();
#pragma unroll
    for (int k = 0; k < 32; k += 8)
        out[(size_t)(c0 + ty + k) * R + r0 + tx] = (f16)tile[tx][ty + k];
}

// ---------------- GEMM core (128x128 tile, BK=64, 4 waves, swizzled LDS) ----------------

__device__ __forceinline__ void gemm_core(const f16* __restrict__ A, const f16* __restrict__ Bt,
                                          int K, int m0, int n0,
                                          f16* lA, f16* lB, f4 acc[4][4]) {
    const int tid = threadIdx.x, lane = tid & 63, wave = tid >> 6;
    const int wm = (wave >> 1) * 64, wn = (wave & 1) * 64;
    for (int k0 = 0; k0 < K; k0 += 64) {
        __syncthreads();
#pragma unroll
        for (int i = 0; i < 4; i++) {
            int s = i * 256 + wave * 64 + lane;
            int row = s >> 3;
            int gc = ((s & 7) ^ (row & 7)) * 8;
            gload16(A + (size_t)(m0 + row) * K + k0 + gc, lA + (i * 256 + wave * 64) * 8);
        }
#pragma unroll
        for (int i = 0; i < 4; i++) {
            int s = i * 256 + wave * 64 + lane;
            int row = s >> 3;
            int gc = ((s & 7) ^ (row & 7)) * 8;
            gload16(Bt + (size_t)(n0 + row) * K + k0 + gc, lB + (i * 256 + wave * 64) * 8);
        }
        __syncthreads();
#pragma unroll
        for (int kk = 0; kk < 2; kk++) {
            h8 af[4], bg[4];
#pragma unroll
            for (int im = 0; im < 4; im++) {
                int row = wm + im * 16 + (lane & 15);
                int pc = (kk * 4 + (lane >> 4)) ^ (row & 7);
                af[im] = *(const h8*)(lA + row * 64 + pc * 8);
            }
#pragma unroll
            for (int in = 0; in < 4; in++) {
                int row = wn + in * 16 + (lane & 15);
                int pc = (kk * 4 + (lane >> 4)) ^ (row & 7);
                bg[in] = *(const h8*)(lB + row * 64 + pc * 8);
            }
#pragma unroll
            for (int im = 0; im < 4; im++)
#pragma unroll
                for (int in = 0; in < 4; in++)
                    acc[im][in] = MFMA(af[im], bg[in], acc[im][in]);
        }
    }
}

// ---------------- QKV GEMM: Q (prescaled), K [BH][T][64] f16; V [BH][T/32][64][32] bf16 ----------------

__global__ __launch_bounds__(256) void qkv_gemm(const f16* __restrict__ A, const f16* __restrict__ Bt,
                                                const float* __restrict__ bias,
                                                f16* __restrict__ Qo, f16* __restrict__ Ko,
                                                unsigned short* __restrict__ Vo) {
    __shared__ f16 lA[128 * 64], lB[128 * 64];
    f4 acc[4][4];
    const f4 zz = {0.f, 0.f, 0.f, 0.f};
#pragma unroll
    for (int i = 0; i < 4; i++)
#pragma unroll
        for (int j = 0; j < 4; j++) acc[i][j] = zz;

    const int swz = (blockIdx.x & 7) * 192 + (blockIdx.x >> 3);  // XCD-chunked (1536 = 8*192)
    const int nb = swz % 24, mb = swz / 24;
    gemm_core(A, Bt, 1024, mb * 128, nb * 128, lA, lB, acc);

    const int lane = threadIdx.x & 63, wave = threadIdx.x >> 6;
    const int wm = (wave >> 1) * 64, wn = (wave & 1) * 64;
#pragma unroll
    for (int im = 0; im < 4; im++) {
        int m4 = mb * 128 + wm + im * 16 + (lane >> 4) * 4;
        int b = m4 >> 11, t0 = m4 & 2047;
#pragma unroll
        for (int in = 0; in < 4; in++) {
            int n = nb * 128 + wn + in * 16 + (lane & 15);
            float bb = bias[n];
            int sec = n >> 10, cc = n & 1023, hh = cc >> 6, d = cc & 63;
            if (sec == 2) {
                // V tiled [kt][64][32] bf16: addr = bh*131072 + (t/32)*2048 + d*32 + (t&31)
                u16x4 pv;
#pragma unroll
                for (int r = 0; r < 4; r++) pv[r] = bf16rn(acc[im][in][r] + bb);
                *(u16x4*)(Vo + (size_t)(b * 16 + hh) * 131072 + (t0 >> 5) * 2048 + d * 32 +
                          (t0 & 31)) = pv;
            } else {
                f16* dst = sec ? Ko : Qo;
                float sc = sec ? 1.0f : QSCALE;  // Q prescaled for base-2 softmax
                size_t base = ((size_t)(b * 16 + hh) * 2048 + t0) * 64 + d;
#pragma unroll
                for (int r = 0; r < 4; r++)
                    dst[base + (size_t)r * 64] = (f16)((acc[im][in][r] + bb) * sc);
            }
        }
    }
}

// ---------------- Proj GEMM: f32 output + bias ----------------

__global__ __launch_bounds__(256) void proj_gemm(const f16* __restrict__ A, const f16* __restrict__ Bt,
                                                 const float* __restrict__ bias,
                                                 float* __restrict__ out) {
    __shared__ f16 lA[128 * 64], lB[128 * 64];
    f4 acc[4][4];
    const f4 zz = {0.f, 0.f, 0.f, 0.f};
#pragma unroll
    for (int i = 0; i < 4; i++)
#pragma unroll
        for (int j = 0; j < 4; j++) acc[i][j] = zz;

    const int swz = (blockIdx.x & 7) * 64 + (blockIdx.x >> 3);  // XCD-chunked (512 = 8*64)
    const int nb = swz & 7, mb = swz >> 3;
    gemm_core(A, Bt, 1024, mb * 128, nb * 128, lA, lB, acc);

    const int lane = threadIdx.x & 63, wave = threadIdx.x >> 6;
    const int wm = (wave >> 1) * 64, wn = (wave & 1) * 64;
#pragma unroll
    for (int im = 0; im < 4; im++) {
        int m4 = mb * 128 + wm + im * 16 + (lane >> 4) * 4;
#pragma unroll
        for (int in = 0; in < 4; in++) {
            int n = nb * 128 + wn + in * 16 + (lane & 15);
            float bb = bias[n];
#pragma unroll
            for (int r = 0; r < 4; r++)
                out[(size_t)(m4 + r) * 1024 + n] = acc[im][in][r] + bb;
        }
    }
}

// ---------------- Flash attention: FUSED complementary pair, shared K/V stream ----------------
// Q(prescaled),K: [BH][2048][64] f16; V: [BH][T/32][64][32] bf16 (kt-tiled); O: [B][2048][1024] f16
// Grid 2048 x 64 threads. Block p processes q-tiles A=63-p AND B=p of bh in ONE loop:
// kt = 0..63-p, each K/V tile loaded ONCE (K via gload_lds->LDS, V->reg ping-pong);
// A updated every kt, B updated when kt <= p. Compute = 65 tile-updates/block (uniform);
// loads = 64-p (25% total K/V traffic cut vs two phases); dual-q iterations give two
// independent QK/softmax/PV chains per loaded tile (ILP for the latency-bound slot).
// K-frags read from LDS once, shared by both chains. No-max bf16 softmax (R18):
// P = 2^S, PV in bf16 MFMA. vmcnt(8) waits only last iteration's 8 loads. Zero barriers.

#define ASM_VMCNT(N) asm volatile("s_waitcnt vmcnt(" #N ")" ::: "memory")

__device__ __forceinline__ void sm_pv(f16x& s, float& lpart, f16x& y0, f16x& y1,
                                      const s8 (&vf)[2][2]) {
    // no-shift softmax: P = 2^S; tree-sum l
    float ps[16];
#pragma unroll
    for (int r = 0; r < 16; r++) {
        ps[r] = fexp2(s[r]);
        s[r] = ps[r];
    }
#pragma unroll
    for (int m = 1; m < 16; m <<= 1)
#pragma unroll
        for (int r = 0; r < 16; r += 2 * m) ps[r] += ps[r + m];
    lpart += ps[0];

    // P -> PV A-fragments (bf16): 8 cvt_pk_bf16 + 4 permlane32_swap (layout HW-verified R9)
    s8 pa[2];
    {
        unsigned a0 = pkb(s[0], s[1]), a1 = pkb(s[2], s[3]);
        unsigned b0 = pkb(s[4], s[5]), b1 = pkb(s[6], s[7]);
        plswap(a0, b0); plswap(a1, b1);
        u4 w0; w0[0] = a0; w0[1] = a1; w0[2] = b0; w0[3] = b1;
        pa[0] = __builtin_bit_cast(s8, w0);
        unsigned c0 = pkb(s[8], s[9]), c1 = pkb(s[10], s[11]);
        unsigned d0 = pkb(s[12], s[13]), d1 = pkb(s[14], s[15]);
        plswap(c0, d0); plswap(c1, d1);
        u4 w1; w1[0] = c0; w1[1] = c1; w1[2] = d0; w1[3] = d1;
        pa[1] = __builtin_bit_cast(s8, w1);
    }

    __builtin_amdgcn_s_setprio(1);
#pragma unroll
    for (int ks = 0; ks < 2; ks++) {
        y0 = MFMA32B(pa[ks], vf[ks][0], y0);
        y1 = MFMA32B(pa[ks], vf[ks][1], y1);
    }
    __builtin_amdgcn_s_setprio(0);
}

__device__ __forceinline__ void attn_tile(int kt, int qtA, int qtB, int nt,
                                          int lane, int hi, int ln,
                                          const f16* __restrict__ Kb,
                                          const unsigned short* __restrict__ Vb,
                                          const f16* lKcur, f16* lKnxt,
                                          const h8 (&qfA)[4], const h8 (&qfB)[4],
                                          s8 (&vf)[2][2], s8 (&vfn)[2][2],
                                          float& lpA, float& lpB,
                                          f16x& yA0, f16x& yA1, f16x& yB0, f16x& yB1) {
    if (kt + 1 < nt) {
        // K(kt+1) -> other LDS buffer (4 x gload16, pre-swizzled source)
#pragma unroll
        for (int i = 0; i < 4; i++) {
            int s = i * 64 + lane;
            int row = s >> 3;
            int gc = ((s & 7) ^ (row & 7)) * 8;
            gload16(Kb + (size_t)((kt + 1) * 32 + row) * 64 + gc, lKnxt + i * 512);
        }
        // V(kt+1) -> other register set (4 x dwordx4); kt-tiled: lane-consecutive lines
#pragma unroll
        for (int ks = 0; ks < 2; ks++)
#pragma unroll
            for (int j = 0; j < 2; j++)
                vfn[ks][j] = *(const s8*)(Vb + (size_t)(kt + 1) * 2048 + (j * 32 + ln) * 32 +
                                          ks * 16 + hi * 8);
        ASM_VMCNT(8);  // wait only last iteration's 8 loads; current 8 stay in flight
    } else {
        ASM_VMCNT(0);
    }
    __builtin_amdgcn_sched_barrier(0);

    // K fragments from LDS once, shared by A and B chains
    h8 kr[4];
#pragma unroll
    for (int dd = 0; dd < 4; dd++) {
        const int c = (dd * 2 + hi) ^ (ln & 7);  // swizzled 16B-chunk index
        kr[dd] = *(const h8*)(lKcur + ln * 64 + c * 8);
    }

    // S_A = K.Q_A^T
    f16x sA;
#pragma unroll
    for (int r = 0; r < 16; r++) sA[r] = 0.f;
    __builtin_amdgcn_s_setprio(1);
#pragma unroll
    for (int dd = 0; dd < 4; dd++) sA = MFMA32(kr[dd], qfA[dd], sA);
    __builtin_amdgcn_s_setprio(0);

    if (kt == qtA) {  // A diagonal: mask k-local kl > ln
#pragma unroll
        for (int r = 0; r < 16; r++) {
            int kl = (r & 3) + 8 * (r >> 2) + 4 * hi;
            if (kl > ln) sA[r] = -3e38f;
        }
    }

    if (kt <= qtB) {  // B active (wave-uniform branch)
        f16x sB;
#pragma unroll
        for (int r = 0; r < 16; r++) sB[r] = 0.f;
        __builtin_amdgcn_s_setprio(1);
#pragma unroll
        for (int dd = 0; dd < 4; dd++) sB = MFMA32(kr[dd], qfB[dd], sB);
        __builtin_amdgcn_s_setprio(0);
        if (kt == qtB) {
#pragma unroll
            for (int r = 0; r < 16; r++) {
                int kl = (r & 3) + 8 * (r >> 2) + 4 * hi;
                if (kl > ln) sB[r] = -3e38f;
            }
        }
        sm_pv(sA, lpA, yA0, yA1, vf);
        sm_pv(sB, lpB, yB0, yB1, vf);
    } else {
        sm_pv(sA, lpA, yA0, yA1, vf);
    }
}

__global__ __launch_bounds__(64) void attn_kernel(const f16* __restrict__ Q,
                                                  const f16* __restrict__ K,
                                                  const unsigned short* __restrict__ Vg,
                                                  f16* __restrict__ O) {
    __shared__ f16 lK[2][2048];  // [buf][32 rows x 64]
    const int lane = threadIdx.x;
    const int hi = lane >> 5, ln = lane & 31;
    const int bh = blockIdx.x & 63;
    const int p = (int)(blockIdx.x >> 6);  // 0..31
    const int qtA = 63 - p, qtB = p;
    const int qwA = qtA * 32, qwB = qtB * 32;
    const f16* Qb = Q + (size_t)bh * 2048 * 64;
    const f16* Kb = K + (size_t)bh * 2048 * 64;
    const unsigned short* Vb = Vg + (size_t)bh * 131072;
    const int b = bh >> 4, hh = bh & 15;

    // hoist Q fragments for both q-tiles (B-operand layout)
    h8 qfA[4], qfB[4];
#pragma unroll
    for (int dd = 0; dd < 4; dd++) {
        qfA[dd] = *(const h8*)(Qb + (size_t)(qwA + ln) * 64 + dd * 16 + hi * 8);
        qfB[dd] = *(const h8*)(Qb + (size_t)(qwB + ln) * 64 + dd * 16 + hi * 8);
    }

    float lpA = 0.f, lpB = 0.f;
    f16x yA0, yA1, yB0, yB1;
#pragma unroll
    for (int r = 0; r < 16; r++) { yA0[r] = 0.f; yA1[r] = 0.f; yB0[r] = 0.f; yB1[r] = 0.f; }

    const int nt = qtA + 1;  // loop covers the A range (superset of B's)

    // prologue: K(0) -> lK[0], V(0) -> vfA
    s8 vfA[2][2], vfB[2][2];
#pragma unroll
    for (int i = 0; i < 4; i++) {
        int s = i * 64 + lane;
        int row = s >> 3;
        int gc = ((s & 7) ^ (row & 7)) * 8;
        gload16(Kb + (size_t)row * 64 + gc, &lK[0][i * 512]);
    }
#pragma unroll
    for (int ks = 0; ks < 2; ks++)
#pragma unroll
        for (int j = 0; j < 2; j++)
            vfA[ks][j] = *(const s8*)(Vb + (size_t)(j * 32 + ln) * 32 + ks * 16 + hi * 8);

    for (int kt = 0; kt < nt; kt += 2) {
        attn_tile(kt, qtA, qtB, nt, lane, hi, ln, Kb, Vb, &lK[0][0], &lK[1][0],
                  qfA, qfB, vfA, vfB, lpA, lpB, yA0, yA1, yB0, yB1);
        if (kt + 1 < nt)
            attn_tile(kt + 1, qtA, qtB, nt, lane, hi, ln, Kb, Vb, &lK[1][0], &lK[0][0],
                      qfA, qfB, vfB, vfA, lpA, lpB, yA0, yA1, yB0, yB1);
    }

    // epilogue: normalize + store both q-tiles
    {
        float lT = lpA + __shfl_xor(lpA, 32);
        float inv = 1.0f / lT;
#pragma unroll
        for (int r = 0; r < 16; r++) {
            int crow = (r & 3) + 8 * (r >> 2) + 4 * hi;
            float invr = __shfl(inv, crow);
            size_t base = ((size_t)(b * 2048 + qwA + crow)) * 1024 + hh * 64 + ln;
            O[base] = (f16)(yA0[r] * invr);
            O[base + 32] = (f16)(yA1[r] * invr);
        }
    }
    {
        float lT = lpB + __shfl_xor(lpB, 32);
        float inv = 1.0f / lT;
#pragma unroll
        for (int r = 0; r < 16; r++) {
            int crow = (r & 3) + 8 * (r >> 2) + 4 * hi;
            float invr = __shfl(inv, crow);
            size_t base = ((size_t)(b * 2048 + qwB + crow)) * 1024 + hh * 64 + ln;
            O[base] = (f16)(yB0[r] * invr);
            O[base + 32] = (f16)(yB1[r] * invr);
        }
    }
}

// ---------------- launch ----------------

extern "C" void kernel_launch(void* const* d_in, const int* in_sizes, int n_in,
                              void* d_out, int out_size, void* d_ws, size_t ws_size,
                              hipStream_t stream) {
    const float* x      = (const float*)d_in[0];
    const float* W_attn = (const float*)d_in[1];
    const float* b_attn = (const float*)d_in[2];
    const float* W_proj = (const float*)d_in[3];
    const float* b_proj = (const float*)d_in[4];
    float* out = (float*)d_out;

    char* ws = (char*)d_ws;
    f16* xb  = (f16*)ws;                                   // 16 MB (reused as attn out)
    f16* Wat = (f16*)(ws + 16777216);                      // 6 MB
    f16* Wpt = (f16*)(ws + 16777216 + 6291456);            // 2 MB
    unsigned short* Vt = (unsigned short*)(ws + 16777216 + 6291456 + 2097152);  // 16 MB (bf16)
    f16* Qs  = (f16*)d_out;                                // scratch: first 16 MB of out
    f16* Ks  = (f16*)((char*)d_out + 16777216);            // scratch: second 16 MB of out

    cvt_f16_kernel<<<4096, 256, 0, stream>>>(x, xb, 1048576);
    transpose_cvt<<<dim3(96, 32), dim3(32, 8), 0, stream>>>(W_attn, Wat, 1024, 3072);
    transpose_cvt<<<dim3(32, 32), dim3(32, 8), 0, stream>>>(W_proj, Wpt, 1024, 1024);
    qkv_gemm<<<1536, 256, 0, stream>>>(xb, Wat, b_attn, Qs, Ks, Vt);
    attn_kernel<<<2048, 64, 0, stream>>>(Qs, Ks, Vt, xb);
    proj_gemm<<<512, 256, 0, stream>>>(xb, Wpt, b_proj, out);
}

// Round 21
// 182.626 us; speedup vs baseline: 1.1856x; 1.1033x over previous
//
#include <hip/hip_runtime.h>

typedef _Float16 f16;
typedef __attribute__((ext_vector_type(8))) _Float16 h8;
typedef __attribute__((ext_vector_type(4))) _Float16 h4;
typedef __attribute__((ext_vector_type(8))) short s8;     // 8 bf16 (4 VGPRs)
typedef __attribute__((ext_vector_type(4))) unsigned short u16x4;
typedef __attribute__((ext_vector_type(4))) float f4;
typedef __attribute__((ext_vector_type(16))) float f16x;
typedef __attribute__((ext_vector_type(4))) unsigned u4;

#define MFMA(a, b, c) __builtin_amdgcn_mfma_f32_16x16x32_f16(a, b, c, 0, 0, 0)
#define MFMA32(a, b, c) __builtin_amdgcn_mfma_f32_32x32x16_f16(a, b, c, 0, 0, 0)
#define MFMA32B(a, b, c) __builtin_amdgcn_mfma_f32_32x32x16_bf16(a, b, c, 0, 0, 0)

// Q prescale: 1/sqrt(64) * log2(e), folded into qkv epilogue -> softmax in base-2
#define QSCALE 0.18033688011112042f

__device__ __forceinline__ void gload16(const void* g, void* l) {
    __builtin_amdgcn_global_load_lds((const __attribute__((address_space(1))) void*)g,
                                     (__attribute__((address_space(3))) void*)l, 16, 0, 0);
}

__device__ __forceinline__ float fexp2(float x) {
    float r;
    asm("v_exp_f32 %0, %1" : "=v"(r) : "v"(x));
    return r;
}

// pack 2 f32 -> 2 bf16 in one u32 (low = src0)
__device__ __forceinline__ unsigned pkb(float a, float b) {
    unsigned r;
    asm("v_cvt_pk_bf16_f32 %0, %1, %2" : "=v"(r) : "v"(a), "v"(b));
    return r;
}

// f32 -> bf16 with round-to-nearest-even
__device__ __forceinline__ unsigned short bf16rn(float x) {
    unsigned u = __builtin_bit_cast(unsigned, x);
    u += 0x7fffu + ((u >> 16) & 1u);
    return (unsigned short)(u >> 16);
}

// v_permlane32_swap_b32: a[l>=32] <-> b[l<32]  (both operands modified)
__device__ __forceinline__ void plswap(unsigned& a, unsigned& b) {
    asm volatile("v_permlane32_swap_b32 %0, %1" : "+v"(a), "+v"(b));
}

// ---------------- conversion kernels ----------------

__global__ __launch_bounds__(256) void cvt_f16_kernel(const float* __restrict__ in,
                                                      f16* __restrict__ out, int n8) {
    int i = blockIdx.x * blockDim.x + threadIdx.x;
    if (i >= n8) return;
    const float4* p = (const float4*)in + (size_t)i * 2;
    float4 a = p[0], b = p[1];
    h8 o;
    o[0] = (f16)a.x; o[1] = (f16)a.y; o[2] = (f16)a.z; o[3] = (f16)a.w;
    o[4] = (f16)b.x; o[5] = (f16)b.y; o[6] = (f16)b.z; o[7] = (f16)b.w;
    *((h8*)out + i) = o;
}

// in: [R][Cc] f32 row-major -> out: [Cc][R] f16 row-major
__global__ __launch_bounds__(256) void transpose_cvt(const float* __restrict__ in,
                                                     f16* __restrict__ out, int R, int Cc) {
    __shared__ float tile[32][33];
    int tx = threadIdx.x, ty = threadIdx.y;
    int c0 = blockIdx.x * 32, r0 = blockIdx.y * 32;
#pragma unroll
    for (int k = 0; k < 32; k += 8)
        tile[ty + k][tx] = in[(size_t)(r0 + ty + k) * Cc + c0 + tx];
    __syncthreads();
#pragma unroll
    for (int k = 0; k < 32; k += 8)
        out[(size_t)(c0 + ty + k) * R + r0 + tx] = (f16)tile[tx][ty + k];
}

// ---------------- GEMM core (128x128 tile, BK=64, 4 waves, swizzled LDS) ----------------

__device__ __forceinline__ void gemm_core(const f16* __restrict__ A, const f16* __restrict__ Bt,
                                          int K, int m0, int n0,
                                          f16* lA, f16* lB, f4 acc[4][4]) {
    const int tid = threadIdx.x, lane = tid & 63, wave = tid >> 6;
    const int wm = (wave >> 1) * 64, wn = (wave & 1) * 64;
    for (int k0 = 0; k0 < K; k0 += 64) {
        __syncthreads();
#pragma unroll
        for (int i = 0; i < 4; i++) {
            int s = i * 256 + wave * 64 + lane;
            int row = s >> 3;
            int gc = ((s & 7) ^ (row & 7)) * 8;
            gload16(A + (size_t)(m0 + row) * K + k0 + gc, lA + (i * 256 + wave * 64) * 8);
        }
#pragma unroll
        for (int i = 0; i < 4; i++) {
            int s = i * 256 + wave * 64 + lane;
            int row = s >> 3;
            int gc = ((s & 7) ^ (row & 7)) * 8;
            gload16(Bt + (size_t)(n0 + row) * K + k0 + gc, lB + (i * 256 + wave * 64) * 8);
        }
        __syncthreads();
#pragma unroll
        for (int kk = 0; kk < 2; kk++) {
            h8 af[4], bg[4];
#pragma unroll
            for (int im = 0; im < 4; im++) {
                int row = wm + im * 16 + (lane & 15);
                int pc = (kk * 4 + (lane >> 4)) ^ (row & 7);
                af[im] = *(const h8*)(lA + row * 64 + pc * 8);
            }
#pragma unroll
            for (int in = 0; in < 4; in++) {
                int row = wn + in * 16 + (lane & 15);
                int pc = (kk * 4 + (lane >> 4)) ^ (row & 7);
                bg[in] = *(const h8*)(lB + row * 64 + pc * 8);
            }
#pragma unroll
            for (int im = 0; im < 4; im++)
#pragma unroll
                for (int in = 0; in < 4; in++)
                    acc[im][in] = MFMA(af[im], bg[in], acc[im][in]);
        }
    }
}

// ---------------- QKV GEMM: Q (prescaled), K [BH][T][64] f16; V [BH][T/32][64][32] bf16 ----------------

__global__ __launch_bounds__(256) void qkv_gemm(const f16* __restrict__ A, const f16* __restrict__ Bt,
                                                const float* __restrict__ bias,
                                                f16* __restrict__ Qo, f16* __restrict__ Ko,
                                                unsigned short* __restrict__ Vo) {
    __shared__ f16 lA[128 * 64], lB[128 * 64];
    f4 acc[4][4];
    const f4 zz = {0.f, 0.f, 0.f, 0.f};
#pragma unroll
    for (int i = 0; i < 4; i++)
#pragma unroll
        for (int j = 0; j < 4; j++) acc[i][j] = zz;

    const int swz = (blockIdx.x & 7) * 192 + (blockIdx.x >> 3);  // XCD-chunked (1536 = 8*192)
    const int nb = swz % 24, mb = swz / 24;
    gemm_core(A, Bt, 1024, mb * 128, nb * 128, lA, lB, acc);

    const int lane = threadIdx.x & 63, wave = threadIdx.x >> 6;
    const int wm = (wave >> 1) * 64, wn = (wave & 1) * 64;
#pragma unroll
    for (int im = 0; im < 4; im++) {
        int m4 = mb * 128 + wm + im * 16 + (lane >> 4) * 4;
        int b = m4 >> 11, t0 = m4 & 2047;
#pragma unroll
        for (int in = 0; in < 4; in++) {
            int n = nb * 128 + wn + in * 16 + (lane & 15);
            float bb = bias[n];
            int sec = n >> 10, cc = n & 1023, hh = cc >> 6, d = cc & 63;
            if (sec == 2) {
                // V tiled [kt][64][32] bf16: addr = bh*131072 + (t/32)*2048 + d*32 + (t&31)
                u16x4 pv;
#pragma unroll
                for (int r = 0; r < 4; r++) pv[r] = bf16rn(acc[im][in][r] + bb);
                *(u16x4*)(Vo + (size_t)(b * 16 + hh) * 131072 + (t0 >> 5) * 2048 + d * 32 +
                          (t0 & 31)) = pv;
            } else {
                f16* dst = sec ? Ko : Qo;
                float sc = sec ? 1.0f : QSCALE;  // Q prescaled for base-2 softmax
                size_t base = ((size_t)(b * 16 + hh) * 2048 + t0) * 64 + d;
#pragma unroll
                for (int r = 0; r < 4; r++)
                    dst[base + (size_t)r * 64] = (f16)((acc[im][in][r] + bb) * sc);
            }
        }
    }
}

// ---------------- Proj GEMM: f32 output + bias ----------------

__global__ __launch_bounds__(256) void proj_gemm(const f16* __restrict__ A, const f16* __restrict__ Bt,
                                                 const float* __restrict__ bias,
                                                 float* __restrict__ out) {
    __shared__ f16 lA[128 * 64], lB[128 * 64];
    f4 acc[4][4];
    const f4 zz = {0.f, 0.f, 0.f, 0.f};
#pragma unroll
    for (int i = 0; i < 4; i++)
#pragma unroll
        for (int j = 0; j < 4; j++) acc[i][j] = zz;

    const int swz = (blockIdx.x & 7) * 64 + (blockIdx.x >> 3);  // XCD-chunked (512 = 8*64)
    const int nb = swz & 7, mb = swz >> 3;
    gemm_core(A, Bt, 1024, mb * 128, nb * 128, lA, lB, acc);

    const int lane = threadIdx.x & 63, wave = threadIdx.x >> 6;
    const int wm = (wave >> 1) * 64, wn = (wave & 1) * 64;
#pragma unroll
    for (int im = 0; im < 4; im++) {
        int m4 = mb * 128 + wm + im * 16 + (lane >> 4) * 4;
#pragma unroll
        for (int in = 0; in < 4; in++) {
            int n = nb * 128 + wn + in * 16 + (lane & 15);
            float bb = bias[n];
#pragma unroll
            for (int r = 0; r < 4; r++)
                out[(size_t)(m4 + r) * 1024 + n] = acc[im][in][r] + bb;
        }
    }
}

// ---------------- Flash attention: R18 packaging + kt-tiled V (single-variable A/B) ----------------
// Q(prescaled),K: [BH][2048][64] f16; V: [BH][T/32][64][32] bf16 (kt-tiled); O: [B][2048][1024] f16
// Grid 2048 x 64 threads: block p does q-tiles (63-p) then (p) as two sequential phases ->
// EVERY block: identical 65 loads AND 65 tile-computes (uniform retirement; R20's fused
// variant broke load-uniformity and regressed). 8 blocks/CU flat; zero barriers.
// Per tile: stage K(it+1)->LDS dbuf + V(it+1)->named reg sets, vmcnt(8) waits only last
// tile's 8 loads. No-max bf16 softmax (R18): P = 2^S, PV in bf16 MFMA; kt-tiled V makes
// PV reads lane-consecutive 64B lines (R19/R20-proven layout, ~4x less V-side L2 read).

#define ASM_VMCNT(N) asm volatile("s_waitcnt vmcnt(" #N ")" ::: "memory")

__device__ __forceinline__ void attn_tile(int k0, bool last, bool stage_next,
                                          int lane, int hi, int ln,
                                          const f16* __restrict__ Kb,
                                          const unsigned short* __restrict__ Vb,
                                          const f16* lKcur, f16* lKnxt,
                                          const h8 (&qf)[4], s8 (&vf)[2][2], s8 (&vfn)[2][2],
                                          float& lpart, f16x& y0, f16x& y1) {
    if (stage_next) {
        // K(it+1) -> other LDS buffer (4 x gload16)
#pragma unroll
        for (int i = 0; i < 4; i++) {
            int s = i * 64 + lane;
            int row = s >> 3;
            int gc = ((s & 7) ^ (row & 7)) * 8;
            gload16(Kb + (size_t)(k0 + 32 + row) * 64 + gc, lKnxt + i * 512);
        }
        // V(it+1) -> other register set (4 x dwordx4); kt-tiled: lane-consecutive lines
#pragma unroll
        for (int ks = 0; ks < 2; ks++)
#pragma unroll
            for (int j = 0; j < 2; j++)
                vfn[ks][j] = *(const s8*)(Vb + (size_t)((k0 >> 5) + 1) * 2048 +
                                          (j * 32 + ln) * 32 + ks * 16 + hi * 8);
        ASM_VMCNT(8);  // wait only last tile's 8 loads; current 8 stay in flight
    } else {
        ASM_VMCNT(0);
    }
    __builtin_amdgcn_sched_barrier(0);

    // S^T = K.Q^T (A = K rows from LDS, B = Q regs); lane owns q = qw+ln
    f16x s0;
#pragma unroll
    for (int r = 0; r < 16; r++) s0[r] = 0.f;
    __builtin_amdgcn_s_setprio(1);
#pragma unroll
    for (int dd = 0; dd < 4; dd++) {
        const int c = (dd * 2 + hi) ^ (ln & 7);  // swizzled 16B-chunk index
        h8 ka = *(const h8*)(lKcur + ln * 64 + c * 8);
        s0 = MFMA32(ka, qf[dd], s0);
    }
    __builtin_amdgcn_s_setprio(0);

    if (last) {  // diagonal tile (k0 == qw): mask k-local kl > ln
#pragma unroll
        for (int r = 0; r < 16; r++) {
            int kl = (r & 3) + 8 * (r >> 2) + 4 * hi;
            if (kl > ln) s0[r] = -3e38f;
        }
    }

    // no-shift softmax: P = 2^S (bf16 keeps relative precision at any scale)
    float ls = 0.f;
#pragma unroll
    for (int r = 0; r < 16; r++) {
        float p = fexp2(s0[r]);
        s0[r] = p;
        ls += p;
    }
    lpart += ls;

    // P -> PV A-fragments (bf16): 8 cvt_pk_bf16 + 4 permlane32_swap (layout HW-verified R9)
    s8 pa[2];
    {
        unsigned a0 = pkb(s0[0], s0[1]), a1 = pkb(s0[2], s0[3]);
        unsigned b0 = pkb(s0[4], s0[5]), b1 = pkb(s0[6], s0[7]);
        plswap(a0, b0); plswap(a1, b1);
        u4 w0; w0[0] = a0; w0[1] = a1; w0[2] = b0; w0[3] = b1;
        pa[0] = __builtin_bit_cast(s8, w0);
        unsigned c0 = pkb(s0[8], s0[9]), c1 = pkb(s0[10], s0[11]);
        unsigned d0 = pkb(s0[12], s0[13]), d1 = pkb(s0[14], s0[15]);
        plswap(c0, d0); plswap(c1, d1);
        u4 w1; w1[0] = c0; w1[1] = c1; w1[2] = d0; w1[3] = d1;
        pa[1] = __builtin_bit_cast(s8, w1);
    }

    // Y += P V  (V prefetched into regs one tile ago; no wait needed)
    __builtin_amdgcn_s_setprio(1);
#pragma unroll
    for (int ks = 0; ks < 2; ks++) {
        y0 = MFMA32B(pa[ks], vf[ks][0], y0);
        y1 = MFMA32B(pa[ks], vf[ks][1], y1);
    }
    __builtin_amdgcn_s_setprio(0);
}

__global__ __launch_bounds__(64) void attn_kernel(const f16* __restrict__ Q,
                                                  const f16* __restrict__ K,
                                                  const unsigned short* __restrict__ Vg,
                                                  f16* __restrict__ O) {
    __shared__ f16 lK[2][2048];  // [buf][32 rows x 64]
    const int lane = threadIdx.x;
    const int hi = lane >> 5, ln = lane & 31;
    const int bh = blockIdx.x & 63;
    const int p = (int)(blockIdx.x >> 6);  // 0..31
    const f16* Qb = Q + (size_t)bh * 2048 * 64;
    const f16* Kb = K + (size_t)bh * 2048 * 64;
    const unsigned short* Vb = Vg + (size_t)bh * 131072;
    const int b = bh >> 4, hh = bh & 15;

    for (int ph = 0; ph < 2; ph++) {
        const int qt = ph ? p : 63 - p;  // complementary pair: total 65 tiles/block, uniform
        const int qw = qt * 32;

        // hoist Q fragments (B-operand): Q[qw+ln][dd*16 + hi*8 .. +8]
        h8 qf[4];
#pragma unroll
        for (int dd = 0; dd < 4; dd++)
            qf[dd] = *(const h8*)(Qb + (size_t)(qw + ln) * 64 + dd * 16 + hi * 8);

        float lpart = 0.f;
        f16x y0, y1;
#pragma unroll
        for (int r = 0; r < 16; r++) { y0[r] = 0.f; y1[r] = 0.f; }

        const int nt = qt + 1;  // tiles of 32; last tile k0 == qw

        // prologue: stage K(0) -> lK[0], V(0) -> vfA
        s8 vfA[2][2], vfB[2][2];
#pragma unroll
        for (int i = 0; i < 4; i++) {
            int s = i * 64 + lane;
            int row = s >> 3;
            int gc = ((s & 7) ^ (row & 7)) * 8;
            gload16(Kb + (size_t)row * 64 + gc, &lK[0][i * 512]);
        }
#pragma unroll
        for (int ks = 0; ks < 2; ks++)
#pragma unroll
            for (int j = 0; j < 2; j++)
                vfA[ks][j] = *(const s8*)(Vb + (size_t)(j * 32 + ln) * 32 + ks * 16 + hi * 8);

        for (int it = 0; it < nt; it += 2) {
            attn_tile(it * 32, it == nt - 1, it + 1 < nt, lane, hi, ln, Kb, Vb,
                      &lK[0][0], &lK[1][0], qf, vfA, vfB, lpart, y0, y1);
            if (it + 1 < nt)
                attn_tile((it + 1) * 32, it + 1 == nt - 1, it + 2 < nt, lane, hi, ln, Kb, Vb,
                          &lK[1][0], &lK[0][0], qf, vfB, vfA, lpart, y0, y1);
        }

        // phase epilogue: combine half-lane partials, normalize, store
        float lT = lpart + __shfl_xor(lpart, 32);
        float inv = 1.0f / lT;
#pragma unroll
        for (int r = 0; r < 16; r++) {
            int crow = (r & 3) + 8 * (r >> 2) + 4 * hi;
            float invr = __shfl(inv, crow);
            size_t base = ((size_t)(b * 2048 + qw + crow)) * 1024 + hh * 64 + ln;
            O[base] = (f16)(y0[r] * invr);
            O[base + 32] = (f16)(y1[r] * invr);
        }
    }
}

// ---------------- launch ----------------

extern "C" void kernel_launch(void* const* d_in, const int* in_sizes, int n_in,
                              void* d_out, int out_size, void* d_ws, size_t ws_size,
                              hipStream_t stream) {
    const float* x      = (const float*)d_in[0];
    const float* W_attn = (const float*)d_in[1];
    const float* b_attn = (const float*)d_in[2];
    const float* W_proj = (const float*)d_in[3];
    const float* b_proj = (const float*)d_in[4];
    float* out = (float*)d_out;

    char* ws = (char*)d_ws;
    f16* xb  = (f16*)ws;                                   // 16 MB (reused as attn out)
    f16* Wat = (f16*)(ws + 16777216);                      // 6 MB
    f16* Wpt = (f16*)(ws + 16777216 + 6291456);            // 2 MB
    unsigned short* Vt = (unsigned short*)(ws + 16777216 + 6291456 + 2097152);  // 16 MB (bf16)
    f16* Qs  = (f16*)d_out;                                // scratch: first 16 MB of out
    f16* Ks  = (f16*)((char*)d_out + 16777216);            // scratch: second 16 MB of out

    cvt_f16_kernel<<<4096, 256, 0, stream>>>(x, xb, 1048576);
    transpose_cvt<<<dim3(96, 32), dim3(32, 8), 0, stream>>>(W_attn, Wat, 1024, 3072);
    transpose_cvt<<<dim3(32, 32), dim3(32, 8), 0, stream>>>(W_proj, Wpt, 1024, 1024);
    qkv_gemm<<<1536, 256, 0, stream>>>(xb, Wat, b_attn, Qs, Ks, Vt);
    attn_kernel<<<2048, 64, 0, stream>>>(Qs, Ks, Vt, xb);
    proj_gemm<<<512, 256, 0, stream>>>(xb, Wpt, b_proj, out);
}

// Round 22
// 176.453 us; speedup vs baseline: 1.2271x; 1.0350x over previous
//
#include <hip/hip_runtime.h>

typedef _Float16 f16;
typedef __attribute__((ext_vector_type(8))) _Float16 h8;
typedef __attribute__((ext_vector_type(4))) _Float16 h4;
typedef __attribute__((ext_vector_type(8))) short s8;     // 8 bf16 (4 VGPRs)
typedef __attribute__((ext_vector_type(4))) unsigned short u16x4;
typedef __attribute__((ext_vector_type(4))) float f4;
typedef __attribute__((ext_vector_type(16))) float f16x;
typedef __attribute__((ext_vector_type(4))) unsigned u4;

#define MFMA(a, b, c) __builtin_amdgcn_mfma_f32_16x16x32_f16(a, b, c, 0, 0, 0)
#define MFMA32(a, b, c) __builtin_amdgcn_mfma_f32_32x32x16_f16(a, b, c, 0, 0, 0)
#define MFMA32B(a, b, c) __builtin_amdgcn_mfma_f32_32x32x16_bf16(a, b, c, 0, 0, 0)

// Q prescale: 1/sqrt(64) * log2(e), folded into qkv epilogue -> softmax in base-2
#define QSCALE 0.18033688011112042f

#define ASM_VMCNT(N) asm volatile("s_waitcnt vmcnt(" #N ")" ::: "memory")

__device__ __forceinline__ void gload16(const void* g, void* l) {
    __builtin_amdgcn_global_load_lds((const __attribute__((address_space(1))) void*)g,
                                     (__attribute__((address_space(3))) void*)l, 16, 0, 0);
}

__device__ __forceinline__ float fexp2(float x) {
    float r;
    asm("v_exp_f32 %0, %1" : "=v"(r) : "v"(x));
    return r;
}

// pack 2 f32 -> 2 bf16 in one u32 (low = src0)
__device__ __forceinline__ unsigned pkb(float a, float b) {
    unsigned r;
    asm("v_cvt_pk_bf16_f32 %0, %1, %2" : "=v"(r) : "v"(a), "v"(b));
    return r;
}

// f32 -> bf16 with round-to-nearest-even
__device__ __forceinline__ unsigned short bf16rn(float x) {
    unsigned u = __builtin_bit_cast(unsigned, x);
    u += 0x7fffu + ((u >> 16) & 1u);
    return (unsigned short)(u >> 16);
}

// v_permlane32_swap_b32: a[l>=32] <-> b[l<32]  (both operands modified)
__device__ __forceinline__ void plswap(unsigned& a, unsigned& b) {
    asm volatile("v_permlane32_swap_b32 %0, %1" : "+v"(a), "+v"(b));
}

// ---------------- conversion kernels ----------------

__global__ __launch_bounds__(256) void cvt_f16_kernel(const float* __restrict__ in,
                                                      f16* __restrict__ out, int n8) {
    int i = blockIdx.x * blockDim.x + threadIdx.x;
    if (i >= n8) return;
    const float4* p = (const float4*)in + (size_t)i * 2;
    float4 a = p[0], b = p[1];
    h8 o;
    o[0] = (f16)a.x; o[1] = (f16)a.y; o[2] = (f16)a.z; o[3] = (f16)a.w;
    o[4] = (f16)b.x; o[5] = (f16)b.y; o[6] = (f16)b.z; o[7] = (f16)b.w;
    *((h8*)out + i) = o;
}

// in: [R][Cc] f32 row-major -> out: [Cc][R] f16 row-major
__global__ __launch_bounds__(256) void transpose_cvt(const float* __restrict__ in,
                                                     f16* __restrict__ out, int R, int Cc) {
    __shared__ float tile[32][33];
    int tx = threadIdx.x, ty = threadIdx.y;
    int c0 = blockIdx.x * 32, r0 = blockIdx.y * 32;
#pragma unroll
    for (int k = 0; k < 32; k += 8)
        tile[ty + k][tx] = in[(size_t)(r0 + ty + k) * Cc + c0 + tx];
    __syncthreads();
#pragma unroll
    for (int k = 0; k < 32; k += 8)
        out[(size_t)(c0 + ty + k) * R + r0 + tx] = (f16)tile[tx][ty + k];
}

// ---------------- GEMM core: 128x128 tile, BK=64, 4 waves, 2-PHASE counted-vmcnt ----------------
// Double-buffered LDS (2 x 32KB). Per K-step: STAGE(t+1 -> other buf) | vmcnt(8) (waits
// only tile-t's 8 loads; t+1's 8 stay in flight across the MFMAs) | s_barrier | compute(t)
// | s_barrier (protects buffer reuse). Raw s_barrier, NOT __syncthreads (which would
// re-insert the vmcnt(0) drain this structure exists to remove).

__device__ __forceinline__ void gemm_stage(const f16* __restrict__ A, const f16* __restrict__ Bt,
                                           int K, int m0, int n0, int k0,
                                           f16* la, f16* lb, int tid, int wave) {
#pragma unroll
    for (int i = 0; i < 4; i++) {
        int s = i * 256 + tid;
        int row = s >> 3;
        int gc = ((s & 7) ^ (row & 7)) * 8;
        gload16(A + (size_t)(m0 + row) * K + k0 + gc, la + (i * 256 + wave * 64) * 8);
    }
#pragma unroll
    for (int i = 0; i < 4; i++) {
        int s = i * 256 + tid;
        int row = s >> 3;
        int gc = ((s & 7) ^ (row & 7)) * 8;
        gload16(Bt + (size_t)(n0 + row) * K + k0 + gc, lb + (i * 256 + wave * 64) * 8);
    }
}

__device__ __forceinline__ void gemm_compute(const f16* la, const f16* lb,
                                             int lane, int wm, int wn, f4 acc[4][4]) {
#pragma unroll
    for (int kk = 0; kk < 2; kk++) {
        h8 af[4], bg[4];
#pragma unroll
        for (int im = 0; im < 4; im++) {
            int row = wm + im * 16 + (lane & 15);
            int pc = (kk * 4 + (lane >> 4)) ^ (row & 7);
            af[im] = *(const h8*)(la + row * 64 + pc * 8);
        }
#pragma unroll
        for (int in = 0; in < 4; in++) {
            int row = wn + in * 16 + (lane & 15);
            int pc = (kk * 4 + (lane >> 4)) ^ (row & 7);
            bg[in] = *(const h8*)(lb + row * 64 + pc * 8);
        }
        __builtin_amdgcn_s_setprio(1);
#pragma unroll
        for (int im = 0; im < 4; im++)
#pragma unroll
            for (int in = 0; in < 4; in++)
                acc[im][in] = MFMA(af[im], bg[in], acc[im][in]);
        __builtin_amdgcn_s_setprio(0);
    }
}

__device__ __forceinline__ void gemm_step(const f16* __restrict__ A, const f16* __restrict__ Bt,
                                          int K, int m0, int n0, int t, int nt,
                                          const f16* cA, const f16* cB, f16* nA, f16* nB,
                                          int tid, int lane, int wave, int wm, int wn,
                                          f4 acc[4][4]) {
    if (t + 1 < nt) {
        gemm_stage(A, Bt, K, m0, n0, (t + 1) * 64, nA, nB, tid, wave);
        ASM_VMCNT(8);  // wait tile-t's 8 loads; tile-(t+1)'s 8 stay in flight
    } else {
        ASM_VMCNT(0);
    }
    __builtin_amdgcn_sched_barrier(0);
    __builtin_amdgcn_s_barrier();
    __builtin_amdgcn_sched_barrier(0);
    gemm_compute(cA, cB, lane, wm, wn, acc);
    // all waves' ds_reads of cA/cB consumed before anyone re-stages into them
    asm volatile("s_waitcnt lgkmcnt(0)" ::: "memory");
    __builtin_amdgcn_sched_barrier(0);
    __builtin_amdgcn_s_barrier();
    __builtin_amdgcn_sched_barrier(0);
}

__device__ __forceinline__ void gemm_core(const f16* __restrict__ A, const f16* __restrict__ Bt,
                                          int K, int m0, int n0,
                                          f16* lA0, f16* lB0, f16* lA1, f16* lB1,
                                          f4 acc[4][4]) {
    const int tid = threadIdx.x, lane = tid & 63, wave = tid >> 6;
    const int wm = (wave >> 1) * 64, wn = (wave & 1) * 64;
    const int nt = K >> 6;  // 16 (even) for K=1024

    // prologue: stage tile 0 into buf 0 (its completion is enforced by step-0's vmcnt(8))
    gemm_stage(A, Bt, K, m0, n0, 0, lA0, lB0, tid, wave);

    for (int t = 0; t < nt; t += 2) {
        gemm_step(A, Bt, K, m0, n0, t, nt, lA0, lB0, lA1, lB1, tid, lane, wave, wm, wn, acc);
        gemm_step(A, Bt, K, m0, n0, t + 1, nt, lA1, lB1, lA0, lB0, tid, lane, wave, wm, wn, acc);
    }
}

// ---------------- QKV GEMM: Q (prescaled), K [BH][T][64] f16; V [BH][T/32][64][32] bf16 ----------------

__global__ __launch_bounds__(256) void qkv_gemm(const f16* __restrict__ A, const f16* __restrict__ Bt,
                                                const float* __restrict__ bias,
                                                f16* __restrict__ Qo, f16* __restrict__ Ko,
                                                unsigned short* __restrict__ Vo) {
    __shared__ f16 lA[2][128 * 64], lB[2][128 * 64];
    f4 acc[4][4];
    const f4 zz = {0.f, 0.f, 0.f, 0.f};
#pragma unroll
    for (int i = 0; i < 4; i++)
#pragma unroll
        for (int j = 0; j < 4; j++) acc[i][j] = zz;

    const int swz = (blockIdx.x & 7) * 192 + (blockIdx.x >> 3);  // XCD-chunked (1536 = 8*192)
    const int nb = swz % 24, mb = swz / 24;
    gemm_core(A, Bt, 1024, mb * 128, nb * 128, lA[0], lB[0], lA[1], lB[1], acc);

    const int lane = threadIdx.x & 63, wave = threadIdx.x >> 6;
    const int wm = (wave >> 1) * 64, wn = (wave & 1) * 64;
#pragma unroll
    for (int im = 0; im < 4; im++) {
        int m4 = mb * 128 + wm + im * 16 + (lane >> 4) * 4;
        int b = m4 >> 11, t0 = m4 & 2047;
#pragma unroll
        for (int in = 0; in < 4; in++) {
            int n = nb * 128 + wn + in * 16 + (lane & 15);
            float bb = bias[n];
            int sec = n >> 10, cc = n & 1023, hh = cc >> 6, d = cc & 63;
            if (sec == 2) {
                // V tiled [kt][64][32] bf16: addr = bh*131072 + (t/32)*2048 + d*32 + (t&31)
                u16x4 pv;
#pragma unroll
                for (int r = 0; r < 4; r++) pv[r] = bf16rn(acc[im][in][r] + bb);
                *(u16x4*)(Vo + (size_t)(b * 16 + hh) * 131072 + (t0 >> 5) * 2048 + d * 32 +
                          (t0 & 31)) = pv;
            } else {
                f16* dst = sec ? Ko : Qo;
                float sc = sec ? 1.0f : QSCALE;  // Q prescaled for base-2 softmax
                size_t base = ((size_t)(b * 16 + hh) * 2048 + t0) * 64 + d;
#pragma unroll
                for (int r = 0; r < 4; r++)
                    dst[base + (size_t)r * 64] = (f16)((acc[im][in][r] + bb) * sc);
            }
        }
    }
}

// ---------------- Proj GEMM: f32 output + bias ----------------

__global__ __launch_bounds__(256) void proj_gemm(const f16* __restrict__ A, const f16* __restrict__ Bt,
                                                 const float* __restrict__ bias,
                                                 float* __restrict__ out) {
    __shared__ f16 lA[2][128 * 64], lB[2][128 * 64];
    f4 acc[4][4];
    const f4 zz = {0.f, 0.f, 0.f, 0.f};
#pragma unroll
    for (int i = 0; i < 4; i++)
#pragma unroll
        for (int j = 0; j < 4; j++) acc[i][j] = zz;

    const int swz = (blockIdx.x & 7) * 64 + (blockIdx.x >> 3);  // XCD-chunked (512 = 8*64)
    const int nb = swz & 7, mb = swz >> 3;
    gemm_core(A, Bt, 1024, mb * 128, nb * 128, lA[0], lB[0], lA[1], lB[1], acc);

    const int lane = threadIdx.x & 63, wave = threadIdx.x >> 6;
    const int wm = (wave >> 1) * 64, wn = (wave & 1) * 64;
#pragma unroll
    for (int im = 0; im < 4; im++) {
        int m4 = mb * 128 + wm + im * 16 + (lane >> 4) * 4;
#pragma unroll
        for (int in = 0; in < 4; in++) {
            int n = nb * 128 + wn + in * 16 + (lane & 15);
            float bb = bias[n];
#pragma unroll
            for (int r = 0; r < 4; r++)
                out[(size_t)(m4 + r) * 1024 + n] = acc[im][in][r] + bb;
        }
    }
}

// ---------------- Flash attention: R21 winner (R18 packaging + kt-tiled V) ----------------

__device__ __forceinline__ void attn_tile(int k0, bool last, bool stage_next,
                                          int lane, int hi, int ln,
                                          const f16* __restrict__ Kb,
                                          const unsigned short* __restrict__ Vb,
                                          const f16* lKcur, f16* lKnxt,
                                          const h8 (&qf)[4], s8 (&vf)[2][2], s8 (&vfn)[2][2],
                                          float& lpart, f16x& y0, f16x& y1) {
    if (stage_next) {
        // K(it+1) -> other LDS buffer (4 x gload16)
#pragma unroll
        for (int i = 0; i < 4; i++) {
            int s = i * 64 + lane;
            int row = s >> 3;
            int gc = ((s & 7) ^ (row & 7)) * 8;
            gload16(Kb + (size_t)(k0 + 32 + row) * 64 + gc, lKnxt + i * 512);
        }
        // V(it+1) -> other register set (4 x dwordx4); kt-tiled: lane-consecutive lines
#pragma unroll
        for (int ks = 0; ks < 2; ks++)
#pragma unroll
            for (int j = 0; j < 2; j++)
                vfn[ks][j] = *(const s8*)(Vb + (size_t)((k0 >> 5) + 1) * 2048 +
                                          (j * 32 + ln) * 32 + ks * 16 + hi * 8);
        ASM_VMCNT(8);  // wait only last tile's 8 loads; current 8 stay in flight
    } else {
        ASM_VMCNT(0);
    }
    __builtin_amdgcn_sched_barrier(0);

    // S^T = K.Q^T (A = K rows from LDS, B = Q regs); lane owns q = qw+ln
    f16x s0;
#pragma unroll
    for (int r = 0; r < 16; r++) s0[r] = 0.f;
    __builtin_amdgcn_s_setprio(1);
#pragma unroll
    for (int dd = 0; dd < 4; dd++) {
        const int c = (dd * 2 + hi) ^ (ln & 7);  // swizzled 16B-chunk index
        h8 ka = *(const h8*)(lKcur + ln * 64 + c * 8);
        s0 = MFMA32(ka, qf[dd], s0);
    }
    __builtin_amdgcn_s_setprio(0);

    if (last) {  // diagonal tile (k0 == qw): mask k-local kl > ln
#pragma unroll
        for (int r = 0; r < 16; r++) {
            int kl = (r & 3) + 8 * (r >> 2) + 4 * hi;
            if (kl > ln) s0[r] = -3e38f;
        }
    }

    // no-shift softmax: P = 2^S (bf16 keeps relative precision at any scale)
    float ls = 0.f;
#pragma unroll
    for (int r = 0; r < 16; r++) {
        float p = fexp2(s0[r]);
        s0[r] = p;
        ls += p;
    }
    lpart += ls;

    // P -> PV A-fragments (bf16): 8 cvt_pk_bf16 + 4 permlane32_swap (layout HW-verified R9)
    s8 pa[2];
    {
        unsigned a0 = pkb(s0[0], s0[1]), a1 = pkb(s0[2], s0[3]);
        unsigned b0 = pkb(s0[4], s0[5]), b1 = pkb(s0[6], s0[7]);
        plswap(a0, b0); plswap(a1, b1);
        u4 w0; w0[0] = a0; w0[1] = a1; w0[2] = b0; w0[3] = b1;
        pa[0] = __builtin_bit_cast(s8, w0);
        unsigned c0 = pkb(s0[8], s0[9]), c1 = pkb(s0[10], s0[11]);
        unsigned d0 = pkb(s0[12], s0[13]), d1 = pkb(s0[14], s0[15]);
        plswap(c0, d0); plswap(c1, d1);
        u4 w1; w1[0] = c0; w1[1] = c1; w1[2] = d0; w1[3] = d1;
        pa[1] = __builtin_bit_cast(s8, w1);
    }

    // Y += P V  (V prefetched into regs one tile ago; no wait needed)
    __builtin_amdgcn_s_setprio(1);
#pragma unroll
    for (int ks = 0; ks < 2; ks++) {
        y0 = MFMA32B(pa[ks], vf[ks][0], y0);
        y1 = MFMA32B(pa[ks], vf[ks][1], y1);
    }
    __builtin_amdgcn_s_setprio(0);
}

__global__ __launch_bounds__(64) void attn_kernel(const f16* __restrict__ Q,
                                                  const f16* __restrict__ K,
                                                  const unsigned short* __restrict__ Vg,
                                                  f16* __restrict__ O) {
    __shared__ f16 lK[2][2048];  // [buf][32 rows x 64]
    const int lane = threadIdx.x;
    const int hi = lane >> 5, ln = lane & 31;
    const int bh = blockIdx.x & 63;
    const int p = (int)(blockIdx.x >> 6);  // 0..31
    const f16* Qb = Q + (size_t)bh * 2048 * 64;
    const f16* Kb = K + (size_t)bh * 2048 * 64;
    const unsigned short* Vb = Vg + (size_t)bh * 131072;
    const int b = bh >> 4, hh = bh & 15;

    for (int ph = 0; ph < 2; ph++) {
        const int qt = ph ? p : 63 - p;  // complementary pair: total 65 tiles/block, uniform
        const int qw = qt * 32;

        // hoist Q fragments (B-operand): Q[qw+ln][dd*16 + hi*8 .. +8]
        h8 qf[4];
#pragma unroll
        for (int dd = 0; dd < 4; dd++)
            qf[dd] = *(const h8*)(Qb + (size_t)(qw + ln) * 64 + dd * 16 + hi * 8);

        float lpart = 0.f;
        f16x y0, y1;
#pragma unroll
        for (int r = 0; r < 16; r++) { y0[r] = 0.f; y1[r] = 0.f; }

        const int nt = qt + 1;  // tiles of 32; last tile k0 == qw

        // prologue: stage K(0) -> lK[0], V(0) -> vfA
        s8 vfA[2][2], vfB[2][2];
#pragma unroll
        for (int i = 0; i < 4; i++) {
            int s = i * 64 + lane;
            int row = s >> 3;
            int gc = ((s & 7) ^ (row & 7)) * 8;
            gload16(Kb + (size_t)row * 64 + gc, &lK[0][i * 512]);
        }
#pragma unroll
        for (int ks = 0; ks < 2; ks++)
#pragma unroll
            for (int j = 0; j < 2; j++)
                vfA[ks][j] = *(const s8*)(Vb + (size_t)(j * 32 + ln) * 32 + ks * 16 + hi * 8);

        for (int it = 0; it < nt; it += 2) {
            attn_tile(it * 32, it == nt - 1, it + 1 < nt, lane, hi, ln, Kb, Vb,
                      &lK[0][0], &lK[1][0], qf, vfA, vfB, lpart, y0, y1);
            if (it + 1 < nt)
                attn_tile((it + 1) * 32, it + 1 == nt - 1, it + 2 < nt, lane, hi, ln, Kb, Vb,
                          &lK[1][0], &lK[0][0], qf, vfB, vfA, lpart, y0, y1);
        }

        // phase epilogue: combine half-lane partials, normalize, store
        float lT = lpart + __shfl_xor(lpart, 32);
        float inv = 1.0f / lT;
#pragma unroll
        for (int r = 0; r < 16; r++) {
            int crow = (r & 3) + 8 * (r >> 2) + 4 * hi;
            float invr = __shfl(inv, crow);
            size_t base = ((size_t)(b * 2048 + qw + crow)) * 1024 + hh * 64 + ln;
            O[base] = (f16)(y0[r] * invr);
            O[base + 32] = (f16)(y1[r] * invr);
        }
    }
}

// ---------------- launch ----------------

extern "C" void kernel_launch(void* const* d_in, const int* in_sizes, int n_in,
                              void* d_out, int out_size, void* d_ws, size_t ws_size,
                              hipStream_t stream) {
    const float* x      = (const float*)d_in[0];
    const float* W_attn = (const float*)d_in[1];
    const float* b_attn = (const float*)d_in[2];
    const float* W_proj = (const float*)d_in[3];
    const float* b_proj = (const float*)d_in[4];
    float* out = (float*)d_out;

    char* ws = (char*)d_ws;
    f16* xb  = (f16*)ws;                                   // 16 MB (reused as attn out)
    f16* Wat = (f16*)(ws + 16777216);                      // 6 MB
    f16* Wpt = (f16*)(ws + 16777216 + 6291456);            // 2 MB
    unsigned short* Vt = (unsigned short*)(ws + 16777216 + 6291456 + 2097152);  // 16 MB (bf16)
    f16* Qs  = (f16*)d_out;                                // scratch: first 16 MB of out
    f16* Ks  = (f16*)((char*)d_out + 16777216);            // scratch: second 16 MB of out

    cvt_f16_kernel<<<4096, 256, 0, stream>>>(x, xb, 1048576);
    transpose_cvt<<<dim3(96, 32), dim3(32, 8), 0, stream>>>(W_attn, Wat, 1024, 3072);
    transpose_cvt<<<dim3(32, 32), dim3(32, 8), 0, stream>>>(W_proj, Wpt, 1024, 1024);
    qkv_gemm<<<1536, 256, 0, stream>>>(xb, Wat, b_attn, Qs, Ks, Vt);
    attn_kernel<<<2048, 64, 0, stream>>>(Qs, Ks, Vt, xb);
    proj_gemm<<<512, 256, 0, stream>>>(xb, Wpt, b_proj, out);
}